// Round 4
// baseline (264.716 us; speedup 1.0000x reference)
//
#include <hip/hip_runtime.h>

#define NHEADS 16
#define HDIM 128
#define BQ 64          // q rows per work item (16 per wave)
#define BK 64          // k tile width
#define KP 72          // Ps row stride (bf16): 144 B rows, 16B aligned
#define FKSP 136       // fallback kernel K stride
#define NPERSIST 512   // persistent blocks (2 per CU)
#define SCL2 0.12751740487817725f   // (1/sqrt(128)) * log2(e)

typedef float f32x4 __attribute__((ext_vector_type(4)));
typedef short bf16x8 __attribute__((ext_vector_type(8)));
typedef unsigned int u32x4 __attribute__((ext_vector_type(4)));
typedef unsigned int u32x2 __attribute__((ext_vector_type(2)));

// round-to-nearest-even f32 -> bf16, packed pair (finite randn inputs: no NaN guard)
__device__ __forceinline__ unsigned pk2(float a, float b) {
  unsigned ua = __builtin_bit_cast(unsigned, a);
  unsigned ub = __builtin_bit_cast(unsigned, b);
  ua = (ua + 0x7fffu + ((ua >> 16) & 1u)) >> 16;
  ub = (ub + 0x7fffu + ((ub >> 16) & 1u)) >> 16;
  return ua | (ub << 16);
}

// async global->LDS DMA, 16B per lane; lds dst is wave-uniform base (+lane*16 by HW)
__device__ __forceinline__ void gld16(const void* g, void* l) {
  __builtin_amdgcn_global_load_lds((const __attribute__((address_space(1))) unsigned int*)g,
                                   (__attribute__((address_space(3))) unsigned int*)l,
                                   16, 0, 0);
}

// ---------------- prepass v2: per (head, 128-token tile) block ----------------
// K -> bf16 [h][t][d] (coalesced convert); V -> bf16 transposed [h][d][t] via LDS.
__global__ void prepass2(const float* __restrict__ K, const float* __restrict__ V,
                         unsigned short* __restrict__ Kb, unsigned short* __restrict__ Vt,
                         int T) {
  __shared__ __align__(16) unsigned int X[128 * 68];   // [d][token-pair], stride 68 u32
  const int t = (int)threadIdx.x;
  const int h = (int)blockIdx.y;
  const int t0 = (int)blockIdx.x * 128;

  // ---- K convert: thread t handles token row t>>1, 64-d chunk (t&1)*64 ----
  {
    const int r = t >> 1, c = (t & 1) * 64;
    const float* src = K + ((size_t)(t0 + r) * NHEADS + h) * HDIM + c;
    unsigned short* dst = Kb + ((size_t)h * T + t0 + r) * HDIM + c;
#pragma unroll
    for (int i = 0; i < 8; ++i) {
      f32x4 a = *(const f32x4*)(src + i * 8);
      f32x4 b = *(const f32x4*)(src + i * 8 + 4);
      *(u32x4*)(dst + i * 8) =
          (u32x4){pk2(a[0], a[1]), pk2(a[2], a[3]), pk2(b[0], b[1]), pk2(b[2], b[3])};
    }
  }

  // ---- V transpose phase 1: token pair (2p, 2p+1), 32-d chunk dc*32; pack cross-token ----
  {
    const int p = t & 63, dc = t >> 6;
    const float* va = V + ((size_t)(t0 + 2 * p) * NHEADS + h) * HDIM + dc * 32;
    const float* vb = va + NHEADS * HDIM;
#pragma unroll
    for (int j = 0; j < 8; ++j) {
      f32x4 a = *(const f32x4*)(va + j * 4);
      f32x4 b = *(const f32x4*)(vb + j * 4);
#pragma unroll
      for (int e = 0; e < 4; ++e)
        X[(dc * 32 + j * 4 + e) * 68 + p] = pk2(a[e], b[e]);   // bank (4d+p)%32: 2-way, free
    }
  }
  __syncthreads();

  // ---- phase 2: read d-rows coalesced, write Vt[h][d][t] 128B contiguous ----
  {
    const int d = t >> 1, half = t & 1;
    const unsigned int* row = X + d * 68 + half * 32;
    unsigned short* od = Vt + ((size_t)h * HDIM + d) * T + t0 + half * 64;
#pragma unroll
    for (int j = 0; j < 8; ++j)
      *(u32x4*)(od + j * 8) = *(const u32x4*)(row + j * 4);
  }
}

// ---------------- setup: LPT order of q-blocks + work counter ----------------
__global__ void setup_sched(const int* __restrict__ cu, int ncu, int T,
                            int* __restrict__ order, int* __restrict__ cnt, int persist) {
  __shared__ int cost[1024], idx[1024];
  const int nqb = T / BQ;
  for (int qb = (int)threadIdx.x; qb < nqb; qb += blockDim.x) {
    const int q0 = qb * BQ;
    int klo0 = 0;
    for (int i = 1; i < ncu - 1; ++i) { int c = cu[i]; if (c <= q0) klo0 = c; }
    cost[qb] = ((q0 + BQ - 1 - (klo0 & ~(BK - 1))) >> 6) + 1;
    idx[qb] = qb;
  }
  __syncthreads();
  if (threadIdx.x == 0) {
    for (int i = 0; i < nqb - 1; ++i) {      // selection sort, descending cost
      int b = i;
      for (int j = i + 1; j < nqb; ++j) if (cost[j] > cost[b]) b = j;
      int tc = cost[i]; cost[i] = cost[b]; cost[b] = tc;
      int ti = idx[i]; idx[i] = idx[b]; idx[b] = ti;
    }
    *cnt = persist;
  }
  __syncthreads();
  for (int qb = (int)threadIdx.x; qb < nqb; qb += blockDim.x) order[qb] = idx[qb];
}

// ---------------- main kernel: persistent blocks + dynamic LPT queue ----------------
__launch_bounds__(256, 2)
__global__ void varlen_attn_v4(const float* __restrict__ Q,
                               const unsigned short* __restrict__ Kb,
                               const unsigned short* __restrict__ VtG,
                               const int* __restrict__ cu,
                               float* __restrict__ Out, int T, int ncu,
                               const int* __restrict__ order, int* __restrict__ cnt,
                               int nItems) {
  __shared__ __align__(16) unsigned short Ks[2][BK * HDIM];   // [k][d], chunk ^= (k&7)
  __shared__ __align__(16) unsigned short Vt[2][HDIM * BK];   // [d][k], chunk ^= (d&7)
  __shared__ __align__(16) unsigned short Ps[4][16 * KP];     // per-wave P [q][k]
  __shared__ int s_item;

  const int t = (int)threadIdx.x, w = t >> 6, l = t & 63;
  const int lam = l & 15, g = l >> 4;
  const int krow_b = 16 * w + (l >> 4);   // K staging: lane's row (+4i), chunk l&15
  const int kchunk = l & 15;
  const int vrow_b = 32 * w + (l >> 3);   // V staging: lane's row (+8i), chunk l&7
  const int vchunk = l & 7;

  int it = (int)blockIdx.x;
  while (it < nItems) {
    const int h = it & (NHEADS - 1);
    const int q0 = order[it >> 4] * BQ;
    const int qtok = q0 + 16 * w + lam;
    const int qcl = qtok < T ? qtok : T - 1;

    int klo = 0, klo0 = 0;
    for (int i = 1; i < ncu - 1; ++i) {
      int c = cu[i];
      if (c <= qcl) klo = c;
      if (c <= q0) klo0 = c;
    }
    const int kstart = klo0 & ~(BK - 1);
    int kend = q0 + BQ - 1; if (kend > T - 1) kend = T - 1;
    const int qmaxw = q0 + 16 * w + 15;

    // Q B-fragments (fp32 global -> bf16 regs)
    bf16x8 qf[4];
    {
      const float* qp = Q + ((size_t)qcl * NHEADS + h) * HDIM + g * 8;
#pragma unroll
      for (int dc = 0; dc < 4; ++dc) {
        f32x4 a = *(const f32x4*)(qp + dc * 32);
        f32x4 b = *(const f32x4*)(qp + dc * 32 + 4);
        union { u32x4 u; bf16x8 v; } cvt;
        cvt.u = (u32x4){pk2(a[0], a[1]), pk2(a[2], a[3]), pk2(b[0], b[1]), pk2(b[2], b[3])};
        qf[dc] = cvt.v;
      }
    }

    const unsigned short* KbH = Kb + (size_t)h * T * HDIM;
    const unsigned short* VtH = VtG + (size_t)h * HDIM * T;

    auto stage = [&](int buf, int kt) {
#pragma unroll
      for (int i = 0; i < 4; ++i) {
        const int row = krow_b + 4 * i;
        int ktok = kt + row; if (ktok > T - 1) ktok = T - 1;
        gld16(KbH + (size_t)ktok * HDIM + ((kchunk ^ (row & 7)) * 8),
              (void*)&Ks[buf][(16 * w + 4 * i) * HDIM]);
      }
#pragma unroll
      for (int i = 0; i < 4; ++i) {
        const int d = vrow_b + 8 * i;
        gld16(VtH + (size_t)d * T + kt + ((vchunk ^ (d & 7)) * 8),
              (void*)&Vt[buf][(32 * w + 8 * i) * BK]);
      }
    };

    f32x4 acc[8];
#pragma unroll
    for (int i = 0; i < 8; ++i) acc[i] = (f32x4){0.f, 0.f, 0.f, 0.f};
    float m2 = -1e30f, ll = 0.f;

    int cur = 0;
    stage(0, kstart);
    for (int kt = kstart; kt <= kend; kt += BK) {
      __syncthreads();                         // drains this tile's async loads
      if (kt + BK <= kend) stage(cur ^ 1, kt + BK);

      if (kt <= qmaxw) {
        const unsigned short* KsC = Ks[cur];
        const unsigned short* VtC = Vt[cur];

        f32x4 st[4];
#pragma unroll
        for (int ct = 0; ct < 4; ++ct) {
          st[ct] = (f32x4){0.f, 0.f, 0.f, 0.f};
#pragma unroll
          for (int dc = 0; dc < 4; ++dc) {
            const bf16x8 kf = *(const bf16x8*)(const void*)
                &KsC[(ct * 16 + lam) * HDIM + (((4 * dc + g) ^ (lam & 7)) * 8)];
            st[ct] = __builtin_amdgcn_mfma_f32_16x16x32_bf16(kf, qf[dc], st[ct], 0, 0, 0);
          }
        }

        float tmax = -1e30f;
#pragma unroll
        for (int ct = 0; ct < 4; ++ct) {
#pragma unroll
          for (int r = 0; r < 4; ++r) {
            const int kidx = kt + ct * 16 + 4 * g + r;
            const float x = (kidx >= klo && kidx <= qtok) ? st[ct][r] * SCL2 : -1e30f;
            st[ct][r] = x;
            tmax = fmaxf(tmax, x);
          }
        }
        tmax = fmaxf(tmax, __shfl_xor(tmax, 16));
        tmax = fmaxf(tmax, __shfl_xor(tmax, 32));
        float mn = fmaxf(fmaxf(m2, tmax), -60000.f);
        const float al = exp2f(m2 - mn);

        float rs = 0.f;
#pragma unroll
        for (int ct = 0; ct < 4; ++ct) {
          const float p0 = exp2f(st[ct][0] - mn);
          const float p1 = exp2f(st[ct][1] - mn);
          const float p2 = exp2f(st[ct][2] - mn);
          const float p3 = exp2f(st[ct][3] - mn);
          rs += (p0 + p1) + (p2 + p3);
          *(u32x2*)(&Ps[w][lam * KP + ct * 16 + 4 * g]) = (u32x2){pk2(p0, p1), pk2(p2, p3)};
        }
        rs += __shfl_xor(rs, 16);
        rs += __shfl_xor(rs, 32);
        ll = ll * al + rs;
        m2 = mn;
#pragma unroll
        for (int i = 0; i < 8; ++i) {
          acc[i][0] *= al; acc[i][1] *= al; acc[i][2] *= al; acc[i][3] *= al;
        }

#pragma unroll
        for (int kc = 0; kc < 2; ++kc) {
          const bf16x8 pf = *(const bf16x8*)(const void*)&Ps[w][lam * KP + kc * 32 + g * 8];
#pragma unroll
          for (int dt = 0; dt < 8; ++dt) {
            const bf16x8 vf = *(const bf16x8*)(const void*)
                &VtC[(dt * 16 + lam) * BK + (((4 * kc + g) ^ (lam & 7)) * 8)];
            acc[dt] = __builtin_amdgcn_mfma_f32_16x16x32_bf16(vf, pf, acc[dt], 0, 0, 0);
          }
        }
      }
      cur ^= 1;
    }

    const float inv = ll > 0.f ? 1.f / ll : 0.f;
    if (qtok < T) {
      float* op = Out + ((size_t)qtok * NHEADS + h) * HDIM + 4 * g;
#pragma unroll
      for (int dt = 0; dt < 8; ++dt) {
        f32x4 o = acc[dt];
        o[0] *= inv; o[1] *= inv; o[2] *= inv; o[3] *= inv;
        *(f32x4*)(op + dt * 16) = o;
      }
    }

    __syncthreads();                 // LDS quiesced before next item restages
    if (t == 0) s_item = atomicAdd(cnt, 1);
    __syncthreads();
    it = s_item;
  }
}

// ---------------- fallback (round-2 kernel) if workspace too small ----------------
__launch_bounds__(256, 3)
__global__ void varlen_attn_fb(const float* __restrict__ Q,
                               const float* __restrict__ K,
                               const float* __restrict__ V,
                               const int* __restrict__ cu,
                               float* __restrict__ Out, int T, int ncu) {
  __shared__ __align__(16) unsigned short Ksf[BK * FKSP];
  __shared__ __align__(16) unsigned short Vtf[HDIM * KP];
  __shared__ __align__(16) unsigned short Psf[4][16 * KP];

  const int t = (int)threadIdx.x, w = t >> 6, l = t & 63;
  const int lam = l & 15, g = l >> 4;
  const int h = (int)blockIdx.y, q0 = (int)blockIdx.x * BQ;
  const int qtok = q0 + 16 * w + lam;
  const int qcl = qtok < T ? qtok : T - 1;
  int klo = 0, klo0 = 0;
  for (int i = 1; i < ncu - 1; ++i) {
    int c = cu[i];
    if (c <= qcl) klo = c;
    if (c <= q0) klo0 = c;
  }
  const int kstart = klo0 & ~(BK - 1);
  int kend = q0 + BQ - 1; if (kend > T - 1) kend = T - 1;
  const int qmaxw = q0 + 16 * w + 15;
  bf16x8 qf[4];
  {
    const float* qp = Q + ((size_t)qcl * NHEADS + h) * HDIM + g * 8;
#pragma unroll
    for (int dc = 0; dc < 4; ++dc) {
      f32x4 a = *(const f32x4*)(qp + dc * 32);
      f32x4 b = *(const f32x4*)(qp + dc * 32 + 4);
      union { u32x4 u; bf16x8 v; } cvt;
      cvt.u = (u32x4){pk2(a[0], a[1]), pk2(a[2], a[3]), pk2(b[0], b[1]), pk2(b[2], b[3])};
      qf[dc] = cvt.v;
    }
  }
  f32x4 acc[8];
#pragma unroll
  for (int i = 0; i < 8; ++i) acc[i] = (f32x4){0.f, 0.f, 0.f, 0.f};
  float m2 = -1e30f, ll = 0.f;
  for (int kt = kstart; kt <= kend; kt += BK) {
    __syncthreads();
    {
      const int row = t >> 2, db = (t & 3) * 32;
      int ktok = kt + row; if (ktok > T - 1) ktok = T - 1;
      const float* kp = K + ((size_t)ktok * NHEADS + h) * HDIM + db;
      unsigned short* dst = &Ksf[row * FKSP + db];
#pragma unroll
      for (int i = 0; i < 4; ++i) {
        f32x4 a = *(const f32x4*)(kp + i * 8);
        f32x4 b = *(const f32x4*)(kp + i * 8 + 4);
        *(u32x4*)(dst + i * 8) =
            (u32x4){pk2(a[0], a[1]), pk2(a[2], a[3]), pk2(b[0], b[1]), pk2(b[2], b[3])};
      }
    }
#pragma unroll
    for (int c = 0; c < 2; ++c) {
      const int kb = kt + 16 * w + 8 * c;
#pragma unroll
      for (int dh = 0; dh < 2; ++dh) {
        const int d = dh * 64 + l;
        float vv[8];
#pragma unroll
        for (int j = 0; j < 8; ++j) {
          int ktok = kb + j; if (ktok > T - 1) ktok = T - 1;
          vv[j] = V[((size_t)ktok * NHEADS + h) * HDIM + d];
        }
        *(u32x4*)(&Vtf[d * KP + 16 * w + 8 * c]) =
            (u32x4){pk2(vv[0], vv[1]), pk2(vv[2], vv[3]), pk2(vv[4], vv[5]), pk2(vv[6], vv[7])};
      }
    }
    __syncthreads();
    if (kt > qmaxw) continue;
    f32x4 st[4];
#pragma unroll
    for (int ct = 0; ct < 4; ++ct) {
      st[ct] = (f32x4){0.f, 0.f, 0.f, 0.f};
#pragma unroll
      for (int dc = 0; dc < 4; ++dc) {
        const bf16x8 kf = *(const bf16x8*)(const void*)&Ksf[(ct * 16 + lam) * FKSP + dc * 32 + g * 8];
        st[ct] = __builtin_amdgcn_mfma_f32_16x16x32_bf16(kf, qf[dc], st[ct], 0, 0, 0);
      }
    }
    float tmax = -1e30f;
#pragma unroll
    for (int ct = 0; ct < 4; ++ct) {
#pragma unroll
      for (int r = 0; r < 4; ++r) {
        const int kidx = kt + ct * 16 + 4 * g + r;
        const float x = (kidx >= klo && kidx <= qtok) ? st[ct][r] * SCL2 : -1e30f;
        st[ct][r] = x;
        tmax = fmaxf(tmax, x);
      }
    }
    tmax = fmaxf(tmax, __shfl_xor(tmax, 16));
    tmax = fmaxf(tmax, __shfl_xor(tmax, 32));
    float mn = fmaxf(fmaxf(m2, tmax), -60000.f);
    const float al = exp2f(m2 - mn);
    float rs = 0.f;
#pragma unroll
    for (int ct = 0; ct < 4; ++ct) {
      const float p0 = exp2f(st[ct][0] - mn);
      const float p1 = exp2f(st[ct][1] - mn);
      const float p2 = exp2f(st[ct][2] - mn);
      const float p3 = exp2f(st[ct][3] - mn);
      rs += (p0 + p1) + (p2 + p3);
      *(u32x2*)(&Psf[w][lam * KP + ct * 16 + 4 * g]) = (u32x2){pk2(p0, p1), pk2(p2, p3)};
    }
    rs += __shfl_xor(rs, 16);
    rs += __shfl_xor(rs, 32);
    ll = ll * al + rs;
    m2 = mn;
#pragma unroll
    for (int i = 0; i < 8; ++i) {
      acc[i][0] *= al; acc[i][1] *= al; acc[i][2] *= al; acc[i][3] *= al;
    }
#pragma unroll
    for (int kc = 0; kc < 2; ++kc) {
      const bf16x8 pf = *(const bf16x8*)(const void*)&Psf[w][lam * KP + kc * 32 + g * 8];
#pragma unroll
      for (int dt = 0; dt < 8; ++dt) {
        const bf16x8 vf = *(const bf16x8*)(const void*)&Vtf[(dt * 16 + lam) * KP + kc * 32 + g * 8];
        acc[dt] = __builtin_amdgcn_mfma_f32_16x16x32_bf16(vf, pf, acc[dt], 0, 0, 0);
      }
    }
  }
  const float inv = ll > 0.f ? 1.f / ll : 0.f;
  if (qtok < T) {
    float* op = Out + ((size_t)qtok * NHEADS + h) * HDIM + 4 * g;
#pragma unroll
    for (int dt = 0; dt < 8; ++dt) {
      f32x4 o = acc[dt];
      o[0] *= inv; o[1] *= inv; o[2] *= inv; o[3] *= inv;
      *(f32x4*)(op + dt * 16) = o;
    }
  }
}

extern "C" void kernel_launch(void* const* d_in, const int* in_sizes, int n_in,
                              void* d_out, int out_size, void* d_ws, size_t ws_size,
                              hipStream_t stream) {
  const float* Q = (const float*)d_in[0];
  const float* K = (const float*)d_in[1];
  const float* V = (const float*)d_in[2];
  const int* cu  = (const int*)d_in[3];
  float* out = (float*)d_out;
  const int T = in_sizes[0] / (NHEADS * HDIM);
  const int ncu = in_sizes[3];
  const size_t base = (size_t)2 * NHEADS * T * HDIM * sizeof(unsigned short);  // Kb + Vt
  const size_t need = base + 8192;
  const int nqb = T / BQ;
  if (ws_size >= need && (T % 256) == 0 && nqb <= 1024) {
    unsigned short* Kb = (unsigned short*)d_ws;
    unsigned short* Vt = Kb + (size_t)NHEADS * T * HDIM;
    int* meta = (int*)((char*)d_ws + base);
    int* order = meta;           // nqb ints
    int* cnt = meta + 1536;      // counter, separate cache line region
    const int nItems = nqb * NHEADS;
    const int persist = nItems < NPERSIST ? nItems : NPERSIST;
    prepass2<<<dim3(T / 128, NHEADS), 256, 0, stream>>>(K, V, Kb, Vt, T);
    setup_sched<<<1, 256, 0, stream>>>(cu, ncu, T, order, cnt, persist);
    varlen_attn_v4<<<dim3(persist), 256, 0, stream>>>(Q, Kb, Vt, cu, out, T, ncu,
                                                      order, cnt, nItems);
  } else {
    dim3 grid((T + BQ - 1) / BQ, NHEADS);
    varlen_attn_fb<<<grid, 256, 0, stream>>>(Q, K, V, cu, out, T, ncu);
  }
}

// Round 5
// 181.657 us; speedup vs baseline: 1.4572x; 1.4572x over previous
//
#include <hip/hip_runtime.h>

#define NHEADS 16
#define HDIM 128
#define BQ 64          // q rows per work item (16 per wave)
#define BK 64          // k tile width
#define KP 72          // Ps row stride (bf16): 144 B rows, 16B aligned
#define FKSP 136       // fallback kernel K stride
#define NPERSIST 512   // persistent blocks (2 per CU)
#define SCL2 0.12751740487817725f   // (1/sqrt(128)) * log2(e)

typedef float f32x4 __attribute__((ext_vector_type(4)));
typedef short bf16x8 __attribute__((ext_vector_type(8)));
typedef unsigned int u32x4 __attribute__((ext_vector_type(4)));
typedef unsigned int u32x2 __attribute__((ext_vector_type(2)));

// round-to-nearest-even f32 -> bf16, packed pair (finite randn inputs: no NaN guard)
__device__ __forceinline__ unsigned pk2(float a, float b) {
  unsigned ua = __builtin_bit_cast(unsigned, a);
  unsigned ub = __builtin_bit_cast(unsigned, b);
  ua = (ua + 0x7fffu + ((ua >> 16) & 1u)) >> 16;
  ub = (ub + 0x7fffu + ((ub >> 16) & 1u)) >> 16;
  return ua | (ub << 16);
}

// async global->LDS DMA, 16B per lane; lds dst is wave-uniform base (+lane*16 by HW)
__device__ __forceinline__ void gld16(const void* g, void* l) {
  __builtin_amdgcn_global_load_lds((const __attribute__((address_space(1))) unsigned int*)g,
                                   (__attribute__((address_space(3))) unsigned int*)l,
                                   16, 0, 0);
}

// ---------------- prepass: convert/transpose K,V + (one block) LPT schedule ----------------
// blockIdx.y < NHEADS : K -> bf16 [h][t][d]; V -> bf16 transposed [h][d][t] via LDS tile.
// blockIdx.y == NHEADS, blockIdx.x == 0 : parallel-rank LPT order + work counter init.
__global__ void prepass2(const float* __restrict__ K, const float* __restrict__ V,
                         unsigned short* __restrict__ Kb, unsigned short* __restrict__ Vt,
                         const int* __restrict__ cu, int ncu, int T,
                         int* __restrict__ order, int* __restrict__ cnt, int persist) {
  const int t = (int)threadIdx.x;
  const int h = (int)blockIdx.y;

  if (h == NHEADS) {
    // ---- scheduling block: cost per q-block, parallel rank (descending, index tiebreak) ----
    if (blockIdx.x != 0) return;
    __shared__ int cost[1024];
    const int nqb = T / BQ;
    for (int qb = t; qb < nqb; qb += (int)blockDim.x) {
      const int q0 = qb * BQ;
      int klo0 = 0;
      for (int i = 1; i < ncu - 1; ++i) { int c = cu[i]; if (c <= q0) klo0 = c; }
      cost[qb] = ((q0 + BQ - 1 - (klo0 & ~(BK - 1))) >> 6) + 1;
    }
    __syncthreads();
    for (int qb = t; qb < nqb; qb += (int)blockDim.x) {
      const int c = cost[qb];
      int rank = 0;
      for (int j = 0; j < nqb; ++j) {
        const int cj = cost[j];
        rank += (cj > c) || (cj == c && j < qb);
      }
      order[rank] = qb;
    }
    if (t == 0) *cnt = persist;
    return;
  }

  __shared__ __align__(16) unsigned int X[128 * 68];   // [d][token-pair], stride 68 u32
  const int t0 = (int)blockIdx.x * 128;

  // ---- K convert: thread t handles token row t>>1, 64-d chunk (t&1)*64 ----
  {
    const int r = t >> 1, c = (t & 1) * 64;
    const float* src = K + ((size_t)(t0 + r) * NHEADS + h) * HDIM + c;
    unsigned short* dst = Kb + ((size_t)h * T + t0 + r) * HDIM + c;
#pragma unroll
    for (int i = 0; i < 8; ++i) {
      f32x4 a = *(const f32x4*)(src + i * 8);
      f32x4 b = *(const f32x4*)(src + i * 8 + 4);
      *(u32x4*)(dst + i * 8) =
          (u32x4){pk2(a[0], a[1]), pk2(a[2], a[3]), pk2(b[0], b[1]), pk2(b[2], b[3])};
    }
  }

  // ---- V transpose phase 1: token pair (2p, 2p+1), 32-d chunk dc*32; pack cross-token ----
  {
    const int p = t & 63, dc = t >> 6;
    const float* va = V + ((size_t)(t0 + 2 * p) * NHEADS + h) * HDIM + dc * 32;
    const float* vb = va + NHEADS * HDIM;
#pragma unroll
    for (int j = 0; j < 8; ++j) {
      f32x4 a = *(const f32x4*)(va + j * 4);
      f32x4 b = *(const f32x4*)(vb + j * 4);
#pragma unroll
      for (int e = 0; e < 4; ++e)
        X[(dc * 32 + j * 4 + e) * 68 + p] = pk2(a[e], b[e]);   // bank (4d+p)%32: 2-way, free
    }
  }
  __syncthreads();

  // ---- phase 2: read d-rows coalesced, write Vt[h][d][t] 128B contiguous ----
  {
    const int d = t >> 1, half = t & 1;
    const unsigned int* row = X + d * 68 + half * 32;
    unsigned short* od = Vt + ((size_t)h * HDIM + d) * T + t0 + half * 64;
#pragma unroll
    for (int j = 0; j < 8; ++j)
      *(u32x4*)(od + j * 8) = *(const u32x4*)(row + j * 4);
  }
}

// ---------------- main kernel: persistent blocks + dynamic LPT queue ----------------
__launch_bounds__(256, 2)
__global__ void varlen_attn_v4(const float* __restrict__ Q,
                               const unsigned short* __restrict__ Kb,
                               const unsigned short* __restrict__ VtG,
                               const int* __restrict__ cu,
                               float* __restrict__ Out, int T, int ncu,
                               const int* __restrict__ order, int* __restrict__ cnt,
                               int nItems) {
  __shared__ __align__(16) unsigned short Ks[2][BK * HDIM];   // [k][d], chunk ^= (k&7)
  __shared__ __align__(16) unsigned short Vt[2][HDIM * BK];   // [d][k], chunk ^= (d&7)
  __shared__ __align__(16) unsigned short Ps[4][16 * KP];     // per-wave P [q][k]
  __shared__ int s_item;

  const int t = (int)threadIdx.x, w = t >> 6, l = t & 63;
  const int lam = l & 15, g = l >> 4;
  const int krow_b = 16 * w + (l >> 4);   // K staging: lane's row (+4i), chunk l&15
  const int kchunk = l & 15;
  const int vrow_b = 32 * w + (l >> 3);   // V staging: lane's row (+8i), chunk l&7
  const int vchunk = l & 7;

  int it = (int)blockIdx.x;
  while (it < nItems) {
    const int h = it & (NHEADS - 1);
    const int q0 = order[it >> 4] * BQ;
    const int qtok = q0 + 16 * w + lam;
    const int qcl = qtok < T ? qtok : T - 1;

    int klo = 0, klo0 = 0;
    for (int i = 1; i < ncu - 1; ++i) {
      int c = cu[i];
      if (c <= qcl) klo = c;
      if (c <= q0) klo0 = c;
    }
    const int kstart = klo0 & ~(BK - 1);
    int kend = q0 + BQ - 1; if (kend > T - 1) kend = T - 1;
    const int qmaxw = q0 + 16 * w + 15;

    // Q B-fragments (fp32 global -> bf16 regs)
    bf16x8 qf[4];
    {
      const float* qp = Q + ((size_t)qcl * NHEADS + h) * HDIM + g * 8;
#pragma unroll
      for (int dc = 0; dc < 4; ++dc) {
        f32x4 a = *(const f32x4*)(qp + dc * 32);
        f32x4 b = *(const f32x4*)(qp + dc * 32 + 4);
        union { u32x4 u; bf16x8 v; } cvt;
        cvt.u = (u32x4){pk2(a[0], a[1]), pk2(a[2], a[3]), pk2(b[0], b[1]), pk2(b[2], b[3])};
        qf[dc] = cvt.v;
      }
    }

    const unsigned short* KbH = Kb + (size_t)h * T * HDIM;
    const unsigned short* VtH = VtG + (size_t)h * HDIM * T;

    auto stage = [&](int buf, int kt) {
#pragma unroll
      for (int i = 0; i < 4; ++i) {
        const int row = krow_b + 4 * i;
        int ktok = kt + row; if (ktok > T - 1) ktok = T - 1;
        gld16(KbH + (size_t)ktok * HDIM + ((kchunk ^ (row & 7)) * 8),
              (void*)&Ks[buf][(16 * w + 4 * i) * HDIM]);
      }
#pragma unroll
      for (int i = 0; i < 4; ++i) {
        const int d = vrow_b + 8 * i;
        gld16(VtH + (size_t)d * T + kt + ((vchunk ^ (d & 7)) * 8),
              (void*)&Vt[buf][(32 * w + 8 * i) * BK]);
      }
    };

    f32x4 acc[8];
#pragma unroll
    for (int i = 0; i < 8; ++i) acc[i] = (f32x4){0.f, 0.f, 0.f, 0.f};
    float m2 = -1e30f, ll = 0.f;

    int cur = 0;
    stage(0, kstart);
    for (int kt = kstart; kt <= kend; kt += BK) {
      __syncthreads();                         // drains this tile's async loads
      if (kt + BK <= kend) stage(cur ^ 1, kt + BK);

      if (kt <= qmaxw) {
        const unsigned short* KsC = Ks[cur];
        const unsigned short* VtC = Vt[cur];

        f32x4 st[4];
#pragma unroll
        for (int ct = 0; ct < 4; ++ct) {
          st[ct] = (f32x4){0.f, 0.f, 0.f, 0.f};
#pragma unroll
          for (int dc = 0; dc < 4; ++dc) {
            const bf16x8 kf = *(const bf16x8*)(const void*)
                &KsC[(ct * 16 + lam) * HDIM + (((4 * dc + g) ^ (lam & 7)) * 8)];
            st[ct] = __builtin_amdgcn_mfma_f32_16x16x32_bf16(kf, qf[dc], st[ct], 0, 0, 0);
          }
        }

        float tmax = -1e30f;
#pragma unroll
        for (int ct = 0; ct < 4; ++ct) {
#pragma unroll
          for (int r = 0; r < 4; ++r) {
            const int kidx = kt + ct * 16 + 4 * g + r;
            const float x = (kidx >= klo && kidx <= qtok) ? st[ct][r] * SCL2 : -1e30f;
            st[ct][r] = x;
            tmax = fmaxf(tmax, x);
          }
        }
        tmax = fmaxf(tmax, __shfl_xor(tmax, 16));
        tmax = fmaxf(tmax, __shfl_xor(tmax, 32));
        float mn = fmaxf(fmaxf(m2, tmax), -60000.f);
        const float al = exp2f(m2 - mn);

        float rs = 0.f;
#pragma unroll
        for (int ct = 0; ct < 4; ++ct) {
          const float p0 = exp2f(st[ct][0] - mn);
          const float p1 = exp2f(st[ct][1] - mn);
          const float p2 = exp2f(st[ct][2] - mn);
          const float p3 = exp2f(st[ct][3] - mn);
          rs += (p0 + p1) + (p2 + p3);
          *(u32x2*)(&Ps[w][lam * KP + ct * 16 + 4 * g]) = (u32x2){pk2(p0, p1), pk2(p2, p3)};
        }
        rs += __shfl_xor(rs, 16);
        rs += __shfl_xor(rs, 32);
        ll = ll * al + rs;
        m2 = mn;
#pragma unroll
        for (int i = 0; i < 8; ++i) {
          acc[i][0] *= al; acc[i][1] *= al; acc[i][2] *= al; acc[i][3] *= al;
        }

#pragma unroll
        for (int kc = 0; kc < 2; ++kc) {
          const bf16x8 pf = *(const bf16x8*)(const void*)&Ps[w][lam * KP + kc * 32 + g * 8];
#pragma unroll
          for (int dt = 0; dt < 8; ++dt) {
            const bf16x8 vf = *(const bf16x8*)(const void*)
                &VtC[(dt * 16 + lam) * BK + (((4 * kc + g) ^ (lam & 7)) * 8)];
            acc[dt] = __builtin_amdgcn_mfma_f32_16x16x32_bf16(vf, pf, acc[dt], 0, 0, 0);
          }
        }
      }
      cur ^= 1;
    }

    const float inv = ll > 0.f ? 1.f / ll : 0.f;
    if (qtok < T) {
      float* op = Out + ((size_t)qtok * NHEADS + h) * HDIM + 4 * g;
#pragma unroll
      for (int dt = 0; dt < 8; ++dt) {
        f32x4 o = acc[dt];
        o[0] *= inv; o[1] *= inv; o[2] *= inv; o[3] *= inv;
        *(f32x4*)(op + dt * 16) = o;
      }
    }

    __syncthreads();                 // LDS quiesced before next item restages
    if (t == 0) s_item = atomicAdd(cnt, 1);
    __syncthreads();
    it = s_item;
  }
}

// ---------------- fallback (round-2 kernel) if workspace too small ----------------
__launch_bounds__(256, 3)
__global__ void varlen_attn_fb(const float* __restrict__ Q,
                               const float* __restrict__ K,
                               const float* __restrict__ V,
                               const int* __restrict__ cu,
                               float* __restrict__ Out, int T, int ncu) {
  __shared__ __align__(16) unsigned short Ksf[BK * FKSP];
  __shared__ __align__(16) unsigned short Vtf[HDIM * KP];
  __shared__ __align__(16) unsigned short Psf[4][16 * KP];

  const int t = (int)threadIdx.x, w = t >> 6, l = t & 63;
  const int lam = l & 15, g = l >> 4;
  const int h = (int)blockIdx.y, q0 = (int)blockIdx.x * BQ;
  const int qtok = q0 + 16 * w + lam;
  const int qcl = qtok < T ? qtok : T - 1;
  int klo = 0, klo0 = 0;
  for (int i = 1; i < ncu - 1; ++i) {
    int c = cu[i];
    if (c <= qcl) klo = c;
    if (c <= q0) klo0 = c;
  }
  const int kstart = klo0 & ~(BK - 1);
  int kend = q0 + BQ - 1; if (kend > T - 1) kend = T - 1;
  const int qmaxw = q0 + 16 * w + 15;
  bf16x8 qf[4];
  {
    const float* qp = Q + ((size_t)qcl * NHEADS + h) * HDIM + g * 8;
#pragma unroll
    for (int dc = 0; dc < 4; ++dc) {
      f32x4 a = *(const f32x4*)(qp + dc * 32);
      f32x4 b = *(const f32x4*)(qp + dc * 32 + 4);
      union { u32x4 u; bf16x8 v; } cvt;
      cvt.u = (u32x4){pk2(a[0], a[1]), pk2(a[2], a[3]), pk2(b[0], b[1]), pk2(b[2], b[3])};
      qf[dc] = cvt.v;
    }
  }
  f32x4 acc[8];
#pragma unroll
  for (int i = 0; i < 8; ++i) acc[i] = (f32x4){0.f, 0.f, 0.f, 0.f};
  float m2 = -1e30f, ll = 0.f;
  for (int kt = kstart; kt <= kend; kt += BK) {
    __syncthreads();
    {
      const int row = t >> 2, db = (t & 3) * 32;
      int ktok = kt + row; if (ktok > T - 1) ktok = T - 1;
      const float* kp = K + ((size_t)ktok * NHEADS + h) * HDIM + db;
      unsigned short* dst = &Ksf[row * FKSP + db];
#pragma unroll
      for (int i = 0; i < 4; ++i) {
        f32x4 a = *(const f32x4*)(kp + i * 8);
        f32x4 b = *(const f32x4*)(kp + i * 8 + 4);
        *(u32x4*)(dst + i * 8) =
            (u32x4){pk2(a[0], a[1]), pk2(a[2], a[3]), pk2(b[0], b[1]), pk2(b[2], b[3])};
      }
    }
#pragma unroll
    for (int c = 0; c < 2; ++c) {
      const int kb = kt + 16 * w + 8 * c;
#pragma unroll
      for (int dh = 0; dh < 2; ++dh) {
        const int d = dh * 64 + l;
        float vv[8];
#pragma unroll
        for (int j = 0; j < 8; ++j) {
          int ktok = kb + j; if (ktok > T - 1) ktok = T - 1;
          vv[j] = V[((size_t)ktok * NHEADS + h) * HDIM + d];
        }
        *(u32x4*)(&Vtf[d * KP + 16 * w + 8 * c]) =
            (u32x4){pk2(vv[0], vv[1]), pk2(vv[2], vv[3]), pk2(vv[4], vv[5]), pk2(vv[6], vv[7])};
      }
    }
    __syncthreads();
    if (kt > qmaxw) continue;
    f32x4 st[4];
#pragma unroll
    for (int ct = 0; ct < 4; ++ct) {
      st[ct] = (f32x4){0.f, 0.f, 0.f, 0.f};
#pragma unroll
      for (int dc = 0; dc < 4; ++dc) {
        const bf16x8 kf = *(const bf16x8*)(const void*)&Ksf[(ct * 16 + lam) * FKSP + dc * 32 + g * 8];
        st[ct] = __builtin_amdgcn_mfma_f32_16x16x32_bf16(kf, qf[dc], st[ct], 0, 0, 0);
      }
    }
    float tmax = -1e30f;
#pragma unroll
    for (int ct = 0; ct < 4; ++ct) {
#pragma unroll
      for (int r = 0; r < 4; ++r) {
        const int kidx = kt + ct * 16 + 4 * g + r;
        const float x = (kidx >= klo && kidx <= qtok) ? st[ct][r] * SCL2 : -1e30f;
        st[ct][r] = x;
        tmax = fmaxf(tmax, x);
      }
    }
    tmax = fmaxf(tmax, __shfl_xor(tmax, 16));
    tmax = fmaxf(tmax, __shfl_xor(tmax, 32));
    float mn = fmaxf(fmaxf(m2, tmax), -60000.f);
    const float al = exp2f(m2 - mn);
    float rs = 0.f;
#pragma unroll
    for (int ct = 0; ct < 4; ++ct) {
      const float p0 = exp2f(st[ct][0] - mn);
      const float p1 = exp2f(st[ct][1] - mn);
      const float p2 = exp2f(st[ct][2] - mn);
      const float p3 = exp2f(st[ct][3] - mn);
      rs += (p0 + p1) + (p2 + p3);
      *(u32x2*)(&Psf[w][lam * KP + ct * 16 + 4 * g]) = (u32x2){pk2(p0, p1), pk2(p2, p3)};
    }
    rs += __shfl_xor(rs, 16);
    rs += __shfl_xor(rs, 32);
    ll = ll * al + rs;
    m2 = mn;
#pragma unroll
    for (int i = 0; i < 8; ++i) {
      acc[i][0] *= al; acc[i][1] *= al; acc[i][2] *= al; acc[i][3] *= al;
    }
#pragma unroll
    for (int kc = 0; kc < 2; ++kc) {
      const bf16x8 pf = *(const bf16x8*)(const void*)&Psf[w][lam * KP + kc * 32 + g * 8];
#pragma unroll
      for (int dt = 0; dt < 8; ++dt) {
        const bf16x8 vf = *(const bf16x8*)(const void*)&Vtf[(dt * 16 + lam) * KP + kc * 32 + g * 8];
        acc[dt] = __builtin_amdgcn_mfma_f32_16x16x32_bf16(vf, pf, acc[dt], 0, 0, 0);
      }
    }
  }
  const float inv = ll > 0.f ? 1.f / ll : 0.f;
  if (qtok < T) {
    float* op = Out + ((size_t)qtok * NHEADS + h) * HDIM + 4 * g;
#pragma unroll
    for (int dt = 0; dt < 8; ++dt) {
      f32x4 o = acc[dt];
      o[0] *= inv; o[1] *= inv; o[2] *= inv; o[3] *= inv;
      *(f32x4*)(op + dt * 16) = o;
    }
  }
}

extern "C" void kernel_launch(void* const* d_in, const int* in_sizes, int n_in,
                              void* d_out, int out_size, void* d_ws, size_t ws_size,
                              hipStream_t stream) {
  const float* Q = (const float*)d_in[0];
  const float* K = (const float*)d_in[1];
  const float* V = (const float*)d_in[2];
  const int* cu  = (const int*)d_in[3];
  float* out = (float*)d_out;
  const int T = in_sizes[0] / (NHEADS * HDIM);
  const int ncu = in_sizes[3];
  const size_t base = (size_t)2 * NHEADS * T * HDIM * sizeof(unsigned short);  // Kb + Vt
  const size_t need = base + 8192;
  const int nqb = T / BQ;
  if (ws_size >= need && (T % 256) == 0 && nqb <= 1024) {
    unsigned short* Kb = (unsigned short*)d_ws;
    unsigned short* Vt = Kb + (size_t)NHEADS * T * HDIM;
    int* meta = (int*)((char*)d_ws + base);
    int* order = meta;           // nqb ints
    int* cnt = meta + 1536;      // counter, separate region
    const int nItems = nqb * NHEADS;
    const int persist = nItems < NPERSIST ? nItems : NPERSIST;
    prepass2<<<dim3(T / 128, NHEADS + 1), 256, 0, stream>>>(K, V, Kb, Vt, cu, ncu, T,
                                                            order, cnt, persist);
    varlen_attn_v4<<<dim3(persist), 256, 0, stream>>>(Q, Kb, Vt, cu, out, T, ncu,
                                                      order, cnt, nItems);
  } else {
    dim3 grid((T + BQ - 1) / BQ, NHEADS);
    varlen_attn_fb<<<grid, 256, 0, stream>>>(Q, K, V, cu, out, T, ncu);
  }
}